// Round 7
// baseline (280.115 us; speedup 1.0000x reference)
//
#include <hip/hip_runtime.h>
#include <hip/hip_bf16.h>
#include <math.h>

#define LEN 4096
#define DIM 2048

typedef __attribute__((ext_vector_type(8))) short s16x8;
typedef __attribute__((ext_vector_type(4))) float f32x4;

__device__ inline ushort f2bf(float f) {
  union { float f; unsigned u; } v; v.f = f;
  unsigned r = (v.u + 0x7FFFu + ((v.u >> 16) & 1u)) >> 16;
  return (ushort)r;
}

__device__ inline float bf2f(ushort b) {
  union { unsigned u; float f; } v; v.u = ((unsigned)b) << 16;
  return v.f;
}

__device__ inline void gll16(const void* g, void* l) {
  __builtin_amdgcn_global_load_lds(
      (const __attribute__((address_space(1))) void*)g,
      (__attribute__((address_space(3))) void*)l, 16, 0, 0);
}

// ---------------- weight f32 -> bf16 cast (all 3 in one launch) ----------------
__global__ __launch_bounds__(256) void wconv3(
    const float* __restrict__ Wk, const float* __restrict__ Wr,
    const float* __restrict__ Wv, ushort* __restrict__ Wkb,
    ushort* __restrict__ Wrb, ushort* __restrict__ Wvb) {
  int b = blockIdx.x;                 // 0..12287
  int which = b >> 12;                // 4096 blocks per weight
  int i = (b & 4095) * 1024 + threadIdx.x * 4;
  const float* W = which == 0 ? Wk : which == 1 ? Wr : Wv;
  ushort* O = which == 0 ? Wkb : which == 1 ? Wrb : Wvb;
  float4 v = *(const float4*)(W + i);
  ushort4 o;
  o.x = f2bf(v.x); o.y = f2bf(v.y); o.z = f2bf(v.z); o.w = f2bf(v.w);
  *(ushort4*)(O + i) = o;
}

// ---------------- EMA (exact equivalent of the FFT decay-mix) ----------------
// x_mix[t] = mix*x_mix[t-1] + (1-mix)*x[t],  x_mix[-1] = last_x
// CHUNK=64 with WARM=64: mix<=sigmoid(1)=0.731 -> 0.731^64 ~ 2e-9.
#define CHUNK 64
#define WARM 64
__global__ __launch_bounds__(256) void ema_kernel(
    const float* __restrict__ x,
    const float* __restrict__ mix_k, const float* __restrict__ mix_r,
    const float* __restrict__ lastk, const float* __restrict__ lastr,
    ushort* __restrict__ xmk, ushort* __restrict__ xmr) {
  const int d = blockIdx.y * 256 + threadIdx.x;
  const int c = blockIdx.x;
  const float mk = 1.f / (1.f + expf(-mix_k[d]));
  const float mr = 1.f / (1.f + expf(-mix_r[d]));
  const float omk = 1.f - mk, omr = 1.f - mr;
  float ak, ar;
  const int t0 = c * CHUNK;
  if (c == 0) {
    ak = lastk[d]; ar = lastr[d];
  } else {
    ak = 0.f; ar = 0.f;
#pragma unroll 4
    for (int t = t0 - WARM; t < t0; ++t) {
      float xv = x[(size_t)t * DIM + d];
      ak = fmaf(mk, ak, omk * xv);
      ar = fmaf(mr, ar, omr * xv);
    }
  }
#pragma unroll 4
  for (int t = t0; t < t0 + CHUNK; ++t) {
    float xv = x[(size_t)t * DIM + d];
    ak = fmaf(mk, ak, omk * xv);
    ar = fmaf(mr, ar, omr * xv);
    xmk[(size_t)t * DIM + d] = f2bf(ak);
    xmr[(size_t)t * DIM + d] = f2bf(ar);
  }
}

// ---------------- 4-phase 256x256 BK=64 bf16 GEMM ----------------------------
// C[m,n] = sum_k A[m,k]*B[n,k].  8 waves (2M x 4N), per-wave 128x64 out.
// Same staging/swizzle/LDS as the verified 8-phase m201 port (R5/R6), but
// phases merged 8->4 per iter: each phase = 2 C-quadrants (32 MFMA), so
// 8 barriers/iter instead of 16 (R6 showed cadence-bound at 1409 cy/phase,
// fetch traffic already optimal).
// vmcnt ledger (per-wave queue, 4 loads/phase), steady state:
//   P2 VM4 retires {prevP4: buf1.B(k1), P1: buf1.A(k1)} -> buf1 ready for P3
//   P4 VM4 retires {P2: buf0.B(k2), P3: buf0.A(k2)}     -> buf0 ready for next P1
// Stage-overwrites only after the closing barrier of the last consuming phase:
//   P1 stages buf1.A (last read prevP4) ; P2 stages buf0.B (last read P1)
//   P3 stages buf0.A (last read P2)     ; P4 stages buf1.B (last read P3)
#define BAR() __builtin_amdgcn_s_barrier()
#define LGKM0() asm volatile("s_waitcnt lgkmcnt(0)")
#define VM4() asm volatile("s_waitcnt vmcnt(4)" ::: "memory")

template <int EPI>
__device__ __forceinline__ void gemm8_body(
    const ushort* __restrict__ A, const ushort* __restrict__ B,
    float* __restrict__ Cf, ushort* __restrict__ Cb,
    const ushort* __restrict__ Sig, int bid, ushort* lds0, ushort* lds1) {
  const int N = DIM, K = DIM;
  const int tid = threadIdx.x;
  const int lane = tid & 63;
  const int w = tid >> 6;     // 0..7
  const int wr = w >> 2;      // 0..1
  const int wc = w & 3;       // 0..3
  const int tm = (bid >> 3) * 256;  // 16 M-tiles
  const int tn = (bid & 7) * 256;   // 8 N-tiles

  f32x4 acc[8][4];
#pragma unroll
  for (int i = 0; i < 8; ++i)
#pragma unroll
    for (int j = 0; j < 4; ++j)
      acc[i][j] = (f32x4){0.f, 0.f, 0.f, 0.f};

  const int sr = tid >> 3;          // staging row 0..63
  const int ssw = ((tid & 7) ^ (sr & 7)) << 3;  // inverse-swizzled k-seg (elems)

  auto stA = [&](ushort* buf, int h, int kt) {
    ushort* dst = buf + h * 8192;
    int ke = kt * 64 + ssw;
    gll16(A + (size_t)(tm + h * 128 + sr) * K + ke, dst + tid * 8);
    gll16(A + (size_t)(tm + h * 128 + 64 + sr) * K + ke, dst + 4096 + tid * 8);
  };
  auto stB = [&](ushort* buf, int h, int kt) {
    ushort* dst = buf + 16384 + h * 8192;
    int ke = kt * 64 + ssw;
    gll16(B + (size_t)(tn + h * 128 + sr) * K + ke, dst + tid * 8);
    gll16(B + (size_t)(tn + h * 128 + 64 + sr) * K + ke, dst + 4096 + tid * 8);
  };

  s16x8 af[4][2], bf[4][2];
  auto rdA = [&](const ushort* buf, int qm) {
#pragma unroll
    for (int i = 0; i < 4; ++i)
#pragma unroll
      for (int kk = 0; kk < 2; ++kk) {
        int rr = (qm * 4 + i) * 16 + (lane & 15);   // rr&7 == lane&7
        int segp = ((kk << 2) + (lane >> 4)) ^ (lane & 7);
        af[i][kk] = *(const s16x8*)(buf + wr * 8192 + rr * 64 + segp * 8);
      }
  };
  auto rdB2 = [&](const ushort* buf, int qn) {
#pragma unroll
    for (int j = 0; j < 2; ++j)
#pragma unroll
      for (int kk = 0; kk < 2; ++kk) {
        int nn = wc * 64 + (qn * 2 + j) * 16 + (lane & 15);  // nn&7 == lane&7
        int segp = ((kk << 2) + (lane >> 4)) ^ (lane & 7);
        bf[qn * 2 + j][kk] =
            *(const s16x8*)(buf + 16384 + (nn >> 7) * 8192 + (nn & 127) * 64 + segp * 8);
      }
  };
  // one C-quadrant-row (qm) x both qn halves: 32 MFMA in one setprio region
  auto mm2 = [&](int qm) {
    __builtin_amdgcn_s_setprio(1);
#pragma unroll
    for (int i = 0; i < 4; ++i)
#pragma unroll
      for (int j = 0; j < 4; ++j)
#pragma unroll
        for (int kk = 0; kk < 2; ++kk)
          acc[qm * 4 + i][j] = __builtin_amdgcn_mfma_f32_16x16x32_bf16(
              af[i][kk], bf[j][kk], acc[qm * 4 + i][j], 0, 0, 0);
    __builtin_amdgcn_s_setprio(0);
  };

  // prologue: buf0 <- K0 (all 4 halves), buf1.B <- K1
  stA(lds0, 0, 0); stA(lds0, 1, 0); stB(lds0, 0, 0); stB(lds0, 1, 0);
  stB(lds1, 0, 1); stB(lds1, 1, 1);
  VM4();  // retires oldest 8 = all of buf0
  BAR();

  for (int u = 0; u < 16; ++u) {
    int k1 = 2 * u + 1;
    int k2 = 2 * u + 2 < 32 ? 2 * u + 2 : 31;  // tail: restage tile 31 (unread)
    int k3 = 2 * u + 3 < 32 ? 2 * u + 3 : 31;
    // P1: consume buf0 (A-half0 + all B), prefetch buf1.A(k1)
    rdA(lds0, 0); rdB2(lds0, 0); rdB2(lds0, 1);
    stA(lds1, 0, k1); stA(lds1, 1, k1);
    BAR(); LGKM0(); mm2(0); BAR();
    // P2: consume buf0 (A-half1), prefetch buf0.B(k2)
    rdA(lds0, 1);
    stB(lds0, 0, k2); stB(lds0, 1, k2);
    VM4();
    BAR(); LGKM0(); mm2(1); BAR();
    // P3: consume buf1 (A-half0 + all B), prefetch buf0.A(k2)
    rdA(lds1, 0); rdB2(lds1, 0); rdB2(lds1, 1);
    stA(lds0, 0, k2); stA(lds0, 1, k2);
    BAR(); LGKM0(); mm2(0); BAR();
    // P4: consume buf1 (A-half1), prefetch buf1.B(k3)
    rdA(lds1, 1);
    stB(lds1, 0, k3); stB(lds1, 1, k3);
    VM4();
    BAR(); LGKM0(); mm2(1); BAR();
  }

#pragma unroll
  for (int i = 0; i < 8; ++i)
#pragma unroll
    for (int j = 0; j < 4; ++j) {
      int col = tn + wc * 64 + j * 16 + (lane & 15);
#pragma unroll
      for (int q = 0; q < 4; ++q) {
        int row = tm + wr * 128 + i * 16 + (lane >> 4) * 4 + q;
        float v = acc[i][j][q];
        size_t o = (size_t)row * N + col;
        if (EPI == 0) {
          float rl = v > 0.f ? v : 0.f;
          Cb[o] = f2bf(rl * rl);
        } else if (EPI == 1) {
          Cb[o] = f2bf(1.f / (1.f + expf(-v)));
        } else {
          Cf[o] = bf2f(Sig[o]) * v;
        }
      }
    }
}

// k+r fused, XCD-contiguous swizzle: lbid = (bid&7)*32 + bid>>3.
// XCD j (= bid&7, round-robin dispatch) owns logical blocks [32j, 32j+32):
// one path, 4 contiguous tm panels (A L2-resident), all 8 tn.
__global__ __launch_bounds__(512, 2) void gemm_kr(
    const ushort* __restrict__ Ak, const ushort* __restrict__ Bk,
    ushort* __restrict__ sq,
    const ushort* __restrict__ Ar, const ushort* __restrict__ Br,
    ushort* __restrict__ sig) {
  __shared__ __align__(16) ushort lds[2][32768];
  int lbid = (blockIdx.x & 7) * 32 + (blockIdx.x >> 3);
  if (lbid < 128)
    gemm8_body<0>(Ak, Bk, nullptr, sq, nullptr, lbid, lds[0], lds[1]);
  else
    gemm8_body<1>(Ar, Br, nullptr, sig, nullptr, lbid - 128, lds[0], lds[1]);
}

__global__ __launch_bounds__(512, 2) void gemm_v(
    const ushort* __restrict__ A, const ushort* __restrict__ B,
    float* __restrict__ Cf, const ushort* __restrict__ Sig) {
  __shared__ __align__(16) ushort lds[2][32768];
  int lbid = (blockIdx.x & 7) * 16 + (blockIdx.x >> 3);
  gemm8_body<2>(A, B, Cf, nullptr, Sig, lbid, lds[0], lds[1]);
}

extern "C" void kernel_launch(void* const* d_in, const int* in_sizes, int n_in,
                              void* d_out, int out_size, void* d_ws, size_t ws_size,
                              hipStream_t stream) {
  const float* x    = (const float*)d_in[0];
  const float* Wk   = (const float*)d_in[1];
  const float* Wr   = (const float*)d_in[2];
  const float* Wv   = (const float*)d_in[3];
  const float* mixk = (const float*)d_in[4];
  const float* mixr = (const float*)d_in[5];
  const float* lxk  = (const float*)d_in[6];
  const float* lxr  = (const float*)d_in[7];
  float* out = (float*)d_out;

  char* ws = (char*)d_ws;
  ushort* xmk = (ushort*)(ws);                       // 16 MB
  ushort* xmr = (ushort*)(ws + (16u << 20));         // 16 MB
  ushort* Wkb = (ushort*)(ws + (32u << 20));         // 8 MB
  ushort* Wrb = (ushort*)(ws + (40u << 20));         // 8 MB
  ushort* Wvb = (ushort*)(ws + (48u << 20));         // 8 MB
  ushort* sq  = (ushort*)(ws + (56u << 20));         // 16 MB
  ushort* sig = (ushort*)(ws + (72u << 20));         // 16 MB (bf16 sigmoid(r))

  wconv3<<<3 * 4096, 256, 0, stream>>>(Wk, Wr, Wv, Wkb, Wrb, Wvb);

  ema_kernel<<<dim3(LEN / CHUNK, DIM / 256), 256, 0, stream>>>(
      x, mixk, mixr, lxk, lxr, xmk, xmr);

  gemm_kr<<<256, 512, 0, stream>>>(xmk, Wkb, sq, xmr, Wrb, sig);
  gemm_v<<<128, 512, 0, stream>>>(sq, Wvb, out, sig);
}

// Round 9
// 250.591 us; speedup vs baseline: 1.1178x; 1.1178x over previous
//
#include <hip/hip_runtime.h>
#include <hip/hip_bf16.h>
#include <math.h>

#define LEN 4096
#define DIM 2048

typedef __attribute__((ext_vector_type(8))) short s16x8;
typedef __attribute__((ext_vector_type(4))) float f32x4;

__device__ inline ushort f2bf(float f) {
  union { float f; unsigned u; } v; v.f = f;
  unsigned r = (v.u + 0x7FFFu + ((v.u >> 16) & 1u)) >> 16;
  return (ushort)r;
}

__device__ inline float bf2f(ushort b) {
  union { unsigned u; float f; } v; v.u = ((unsigned)b) << 16;
  return v.f;
}

__device__ inline void gll16(const void* g, void* l) {
  __builtin_amdgcn_global_load_lds(
      (const __attribute__((address_space(1))) void*)g,
      (__attribute__((address_space(3))) void*)l, 16, 0, 0);
}

// ------------- fused prep: EMA (blocks 0..511, first so they start early)
//               + 3x weight f32->bf16 cast (blocks 512..13311) ---------------
// EMA: x_mix[t] = mix*x_mix[t-1] + (1-mix)*x[t], x_mix[-1]=last_x.
// CHUNK=64, WARM=64: mix<=sigmoid(1)=0.731 -> 0.731^64 ~ 2e-9 (< bf16 eps).
#define CHUNK 64
#define WARM 64
__global__ __launch_bounds__(256) void prep_kernel(
    const float* __restrict__ x,
    const float* __restrict__ mix_k, const float* __restrict__ mix_r,
    const float* __restrict__ lastk, const float* __restrict__ lastr,
    ushort* __restrict__ xmk, ushort* __restrict__ xmr,
    const float* __restrict__ Wk, const float* __restrict__ Wr,
    const float* __restrict__ Wv, ushort* __restrict__ Wkb,
    ushort* __restrict__ Wrb, ushort* __restrict__ Wvb) {
  int b = blockIdx.x;
  if (b < 512) {
    // ---- EMA path ----
    const int c = b & 63;                       // time chunk
    const int d = (b >> 6) * 256 + threadIdx.x; // channel
    const float mk = 1.f / (1.f + expf(-mix_k[d]));
    const float mr = 1.f / (1.f + expf(-mix_r[d]));
    const float omk = 1.f - mk, omr = 1.f - mr;
    float ak, ar;
    const int t0 = c * CHUNK;
    if (c == 0) {
      ak = lastk[d]; ar = lastr[d];
    } else {
      ak = 0.f; ar = 0.f;
#pragma unroll 4
      for (int t = t0 - WARM; t < t0; ++t) {
        float xv = x[(size_t)t * DIM + d];
        ak = fmaf(mk, ak, omk * xv);
        ar = fmaf(mr, ar, omr * xv);
      }
    }
#pragma unroll 4
    for (int t = t0; t < t0 + CHUNK; ++t) {
      float xv = x[(size_t)t * DIM + d];
      ak = fmaf(mk, ak, omk * xv);
      ar = fmaf(mr, ar, omr * xv);
      xmk[(size_t)t * DIM + d] = f2bf(ak);
      xmr[(size_t)t * DIM + d] = f2bf(ar);
    }
  } else {
    // ---- weight cast path ----
    int wb = b - 512;                 // 0..12287
    int which = wb >> 12;             // 4096 blocks per weight
    int i = (wb & 4095) * 1024 + threadIdx.x * 4;
    const float* W = which == 0 ? Wk : which == 1 ? Wr : Wv;
    ushort* O = which == 0 ? Wkb : which == 1 ? Wrb : Wvb;
    float4 v = *(const float4*)(W + i);
    ushort4 o;
    o.x = f2bf(v.x); o.y = f2bf(v.y); o.z = f2bf(v.z); o.w = f2bf(v.w);
    *(ushort4*)(O + i) = o;
  }
}

#define BAR() __builtin_amdgcn_s_barrier()
#define LGKM0() asm volatile("s_waitcnt lgkmcnt(0)")
#define VM4() asm volatile("s_waitcnt vmcnt(4)" ::: "memory")
#define VM6() asm volatile("s_waitcnt vmcnt(6)" ::: "memory")

// ---------------- 8-phase 256x256 BK=64 bf16 GEMM (R6 structure) -------------
// C[m,n] = sum_k A[m,k]*B[n,k].  8 waves (2M x 4N), per-wave 128x64 out.
// XOR swizzle seg^=(row&7) both-sides. vmcnt ledger: ph4 VM4 retires
// {prev ph7,ph8; ph1,ph2}; ph8 VM4 retires {ph3..ph6}.
// EPI 0: sq = bf16(relu(acc)^2) ; EPI 1: sig = bf16(sigmoid(acc))
template <int EPI>
__device__ __forceinline__ void gemm8_body(
    const ushort* __restrict__ A, const ushort* __restrict__ B,
    ushort* __restrict__ Cb, int bid, ushort* lds0, ushort* lds1) {
  const int N = DIM, K = DIM;
  const int tid = threadIdx.x;
  const int lane = tid & 63;
  const int w = tid >> 6;
  const int wr = w >> 2;      // 0..1
  const int wc = w & 3;       // 0..3
  const int tm = (bid >> 3) * 256;
  const int tn = (bid & 7) * 256;

  f32x4 acc[8][4];
#pragma unroll
  for (int i = 0; i < 8; ++i)
#pragma unroll
    for (int j = 0; j < 4; ++j)
      acc[i][j] = (f32x4){0.f, 0.f, 0.f, 0.f};

  const int sr = tid >> 3;
  const int ssw = ((tid & 7) ^ (sr & 7)) << 3;

  auto stA = [&](ushort* buf, int h, int kt) {
    ushort* dst = buf + h * 8192;
    int ke = kt * 64 + ssw;
    gll16(A + (size_t)(tm + h * 128 + sr) * K + ke, dst + tid * 8);
    gll16(A + (size_t)(tm + h * 128 + 64 + sr) * K + ke, dst + 4096 + tid * 8);
  };
  auto stB = [&](ushort* buf, int h, int kt) {
    ushort* dst = buf + 16384 + h * 8192;
    int ke = kt * 64 + ssw;
    gll16(B + (size_t)(tn + h * 128 + sr) * K + ke, dst + tid * 8);
    gll16(B + (size_t)(tn + h * 128 + 64 + sr) * K + ke, dst + 4096 + tid * 8);
  };

  s16x8 af[4][2], bf[4][2];
  auto rdA = [&](const ushort* buf, int qm) {
#pragma unroll
    for (int i = 0; i < 4; ++i)
#pragma unroll
      for (int kk = 0; kk < 2; ++kk) {
        int rr = (qm * 4 + i) * 16 + (lane & 15);
        int segp = ((kk << 2) + (lane >> 4)) ^ (lane & 7);
        af[i][kk] = *(const s16x8*)(buf + wr * 8192 + rr * 64 + segp * 8);
      }
  };
  auto rdB2 = [&](const ushort* buf, int qn) {
#pragma unroll
    for (int j = 0; j < 2; ++j)
#pragma unroll
      for (int kk = 0; kk < 2; ++kk) {
        int nn = wc * 64 + (qn * 2 + j) * 16 + (lane & 15);
        int segp = ((kk << 2) + (lane >> 4)) ^ (lane & 7);
        bf[qn * 2 + j][kk] =
            *(const s16x8*)(buf + 16384 + (nn >> 7) * 8192 + (nn & 127) * 64 + segp * 8);
      }
  };
  auto mm = [&](int qm, int qn) {
    __builtin_amdgcn_s_setprio(1);
#pragma unroll
    for (int i = 0; i < 4; ++i)
#pragma unroll
      for (int j = 0; j < 2; ++j)
#pragma unroll
        for (int kk = 0; kk < 2; ++kk)
          acc[qm * 4 + i][qn * 2 + j] = __builtin_amdgcn_mfma_f32_16x16x32_bf16(
              af[i][kk], bf[qn * 2 + j][kk], acc[qm * 4 + i][qn * 2 + j], 0, 0, 0);
    __builtin_amdgcn_s_setprio(0);
  };

  stA(lds0, 0, 0); stA(lds0, 1, 0); stB(lds0, 0, 0); stB(lds0, 1, 0);
  stB(lds1, 0, 1); stB(lds1, 1, 1);
  VM4();
  BAR();

  for (int u = 0; u < 16; ++u) {
    int k1 = 2 * u + 1;
    int k2 = 2 * u + 2 < 32 ? 2 * u + 2 : 31;
    int k3 = 2 * u + 3 < 32 ? 2 * u + 3 : 31;
    rdA(lds0, 0); rdB2(lds0, 0); stA(lds1, 0, k1);
    BAR(); LGKM0(); mm(0, 0); BAR();
    rdB2(lds0, 1); stA(lds1, 1, k1);
    BAR(); LGKM0(); mm(0, 1); BAR();
    rdA(lds0, 1); stB(lds0, 0, k2);
    BAR(); LGKM0(); mm(1, 0); BAR();
    stB(lds0, 1, k2); VM4();
    BAR(); mm(1, 1); BAR();
    rdA(lds1, 0); rdB2(lds1, 0); stA(lds0, 0, k2);
    BAR(); LGKM0(); mm(0, 0); BAR();
    rdB2(lds1, 1); stA(lds0, 1, k2);
    BAR(); LGKM0(); mm(0, 1); BAR();
    rdA(lds1, 1); stB(lds1, 0, k3);
    BAR(); LGKM0(); mm(1, 0); BAR();
    stB(lds1, 1, k3); VM4();
    BAR(); mm(1, 1); BAR();
  }

#pragma unroll
  for (int i = 0; i < 8; ++i)
#pragma unroll
    for (int j = 0; j < 4; ++j) {
      int col = tn + wc * 64 + j * 16 + (lane & 15);
#pragma unroll
      for (int q = 0; q < 4; ++q) {
        int row = tm + wr * 128 + i * 16 + (lane >> 4) * 4 + q;
        float v = acc[i][j][q];
        size_t o = (size_t)row * N + col;
        if (EPI == 0) {
          float rl = v > 0.f ? v : 0.f;
          Cb[o] = f2bf(rl * rl);
        } else {
          Cb[o] = f2bf(1.f / (1.f + expf(-v)));
        }
      }
    }
}

// k+r fused, XCD-contiguous swizzle (32 blocks per XCD, one path each).
__global__ __launch_bounds__(512, 2) void gemm_kr(
    const ushort* __restrict__ Ak, const ushort* __restrict__ Bk,
    ushort* __restrict__ sq,
    const ushort* __restrict__ Ar, const ushort* __restrict__ Br,
    ushort* __restrict__ sig) {
  __shared__ __align__(16) ushort lds[2][32768];
  int lbid = (blockIdx.x & 7) * 32 + (blockIdx.x >> 3);
  if (lbid < 128)
    gemm8_body<0>(Ak, Bk, sq, lbid, lds[0], lds[1]);
  else
    gemm8_body<1>(Ar, Br, sig, lbid - 128, lds[0], lds[1]);
}

// ---------------- gemm_v: 128x256 tile, 256 blocks (full machine) ------------
// 8 waves 2M x 4N -> wave tile 64x64, acc[4][4]. BK=64, 32 K-tiles.
// LDS: 3-buffer ring, 48KB each (A 16KB + B 2x16KB), 144KB total.
// 2 phases per K-tile; stage K-tile u+2 into the ring slot 2 ahead.
// vmcnt ledger (6 loads per K-tile: stA 2 + stB 4): iter u's VM6 retires
// iter (u-1)'s 6 loads -> buffer read at iter u+1 verified landed.
// Ring-overwrite hazard: buffer staged at iter u+1 was last READ at iter u;
// those reads are drained by LGKM0 before iter u's closing BAR, and the
// overwriting gll16s are issued after that BAR -> safe.
// out = bf16->f32(Sig) * acc  (f32 final output)
__global__ __launch_bounds__(512, 2) void gemm_v(
    const ushort* __restrict__ A, const ushort* __restrict__ B,
    float* __restrict__ Cf, const ushort* __restrict__ Sig) {
  __shared__ __align__(16) ushort lds[3 * 24576];  // 144 KB
  const int N = DIM, K = DIM;
  const int tid = threadIdx.x;
  const int lane = tid & 63;
  const int w = tid >> 6;
  const int wr = w >> 2;      // 0..1 (m)
  const int wc = w & 3;       // 0..3 (n)
  int lbid = (blockIdx.x & 7) * 32 + (blockIdx.x >> 3);  // XCD-contiguous
  const int tm = (lbid >> 3) * 128;   // 32 M-tiles
  const int tn = (lbid & 7) * 256;    // 8 N-tiles

  f32x4 acc[4][4];
#pragma unroll
  for (int i = 0; i < 4; ++i)
#pragma unroll
    for (int j = 0; j < 4; ++j)
      acc[i][j] = (f32x4){0.f, 0.f, 0.f, 0.f};

  const int sr = tid >> 3;
  const int ssw = ((tid & 7) ^ (sr & 7)) << 3;

  auto stA = [&](ushort* buf, int kt) {       // A tile 128x64 (2 glls)
    int ke = kt * 64 + ssw;
    gll16(A + (size_t)(tm + sr) * K + ke, buf + tid * 8);
    gll16(A + (size_t)(tm + 64 + sr) * K + ke, buf + 4096 + tid * 8);
  };
  auto stB = [&](ushort* buf, int h, int kt) {  // B half 128x64 (2 glls)
    ushort* dst = buf + 8192 + h * 8192;
    int ke = kt * 64 + ssw;
    gll16(B + (size_t)(tn + h * 128 + sr) * K + ke, dst + tid * 8);
    gll16(B + (size_t)(tn + h * 128 + 64 + sr) * K + ke, dst + 4096 + tid * 8);
  };

  s16x8 af[4][2], bf[4][2];
  auto rdA = [&](const ushort* buf) {
#pragma unroll
    for (int i = 0; i < 4; ++i)
#pragma unroll
      for (int kk = 0; kk < 2; ++kk) {
        int rr = wr * 64 + i * 16 + (lane & 15);   // rr&7 == lane&7
        int segp = ((kk << 2) + (lane >> 4)) ^ (lane & 7);
        af[i][kk] = *(const s16x8*)(buf + rr * 64 + segp * 8);
      }
  };
  auto rdB = [&](const ushort* buf, int qn) {
#pragma unroll
    for (int j = 0; j < 2; ++j)
#pragma unroll
      for (int kk = 0; kk < 2; ++kk) {
        int nn = wc * 64 + (qn * 2 + j) * 16 + (lane & 15);
        int segp = ((kk << 2) + (lane >> 4)) ^ (lane & 7);
        bf[qn * 2 + j][kk] =
            *(const s16x8*)(buf + 8192 + (nn >> 7) * 8192 + (nn & 127) * 64 + segp * 8);
      }
  };
  auto mm16 = [&](int qn) {
    __builtin_amdgcn_s_setprio(1);
#pragma unroll
    for (int i = 0; i < 4; ++i)
#pragma unroll
      for (int j = 0; j < 2; ++j)
#pragma unroll
        for (int kk = 0; kk < 2; ++kk)
          acc[i][qn * 2 + j] = __builtin_amdgcn_mfma_f32_16x16x32_bf16(
              af[i][kk], bf[qn * 2 + j][kk], acc[i][qn * 2 + j], 0, 0, 0);
    __builtin_amdgcn_s_setprio(0);
  };

  ushort* pc = lds;                // current (read)
  ushort* pn = lds + 24576;        // next
  ushort* pn2 = lds + 49152;       // stage target (2 ahead)

  // prologue: k0 -> pc, k1 -> pn (12 loads); VM6 retires k0's 6.
  stA(pc, 0); stB(pc, 0, 0); stB(pc, 1, 0);
  stA(pn, 1); stB(pn, 0, 1); stB(pn, 1, 1);
  VM6();
  BAR();

  for (int u = 0; u < 32; ++u) {
    int kn = u + 2 < 32 ? u + 2 : 31;  // tail: dummy restage (never read)
    // P1: read pc (A + B-half0), stage pn2.A + pn2.B0 (k = u+2)
    rdA(pc); rdB(pc, 0);
    stA(pn2, kn); stB(pn2, 0, kn);
    BAR(); LGKM0(); mm16(0); BAR();
    // P2: read pc (B-half1), stage pn2.B1; VM6 retires iter(u-1)'s 6 -> pn ready
    rdB(pc, 1);
    stB(pn2, 1, kn);
    VM6();
    BAR(); LGKM0(); mm16(1); BAR();
    // rotate ring
    ushort* t = pc; pc = pn; pn = pn2; pn2 = t;
  }

#pragma unroll
  for (int i = 0; i < 4; ++i)
#pragma unroll
    for (int j = 0; j < 4; ++j) {
      int col = tn + wc * 64 + j * 16 + (lane & 15);
#pragma unroll
      for (int q = 0; q < 4; ++q) {
        int row = tm + wr * 64 + i * 16 + (lane >> 4) * 4 + q;
        size_t o = (size_t)row * N + col;
        Cf[o] = bf2f(Sig[o]) * acc[i][j][q];
      }
    }
}

extern "C" void kernel_launch(void* const* d_in, const int* in_sizes, int n_in,
                              void* d_out, int out_size, void* d_ws, size_t ws_size,
                              hipStream_t stream) {
  const float* x    = (const float*)d_in[0];
  const float* Wk   = (const float*)d_in[1];
  const float* Wr   = (const float*)d_in[2];
  const float* Wv   = (const float*)d_in[3];
  const float* mixk = (const float*)d_in[4];
  const float* mixr = (const float*)d_in[5];
  const float* lxk  = (const float*)d_in[6];
  const float* lxr  = (const float*)d_in[7];
  float* out = (float*)d_out;

  char* ws = (char*)d_ws;
  ushort* xmk = (ushort*)(ws);                       // 16 MB
  ushort* xmr = (ushort*)(ws + (16u << 20));         // 16 MB
  ushort* Wkb = (ushort*)(ws + (32u << 20));         // 8 MB
  ushort* Wrb = (ushort*)(ws + (40u << 20));         // 8 MB
  ushort* Wvb = (ushort*)(ws + (48u << 20));         // 8 MB
  ushort* sq  = (ushort*)(ws + (56u << 20));         // 16 MB
  ushort* sig = (ushort*)(ws + (72u << 20));         // 16 MB (bf16 sigmoid(r))

  prep_kernel<<<512 + 3 * 4096, 256, 0, stream>>>(
      x, mixk, mixr, lxk, lxr, xmk, xmr, Wk, Wr, Wv, Wkb, Wrb, Wvb);

  gemm_kr<<<256, 512, 0, stream>>>(xmk, Wkb, sq, xmr, Wrb, sig);
  gemm_v<<<256, 512, 0, stream>>>(sq, Wvb, out, sig);
}